// Round 1
// baseline (307.069 us; speedup 1.0000x reference)
//
#include <hip/hip_runtime.h>

// Problem: L=200 events consumed in pairs -> S=100 scan steps over u[N,N,3],
// N=256. Each (n,m) cell is an independent 100-step chain; the per-node
// dot/exp factors f[t][n] are state-independent and precomputed per block.
//
// Occupancy is hard-capped at 1 wave/SIMD (65536 chains / 64 = 1024 waves on
// 1024 SIMDs), so ALL latency hiding must come from ILP. This version uses a
// depth-10 statically-indexed register ring (no rotation copies -> compiler
// emits counted vmcnt, ~54 dwords/lane in flight) and a widened prologue.
//
// Layout facts:
//   event_list [201,256,256]  (use first 200 rows)
//   a          [200,256,256,3]
//   w          [200,256,1,256]
//   u_begin    [256,256,3]
//   liner_w    [256,3], liner_b [256]
//   out        [100,256,256]  float32

#define NN   256
#define TT   200
#define SS   100
#define DD   10            // register-ring depth in scan steps
#define NG   (SS / DD)     // 10 groups

__global__ __launch_bounds__(256) void fused_scan_kernel(
    const float* __restrict__ timep,   // [2]
    const float* __restrict__ ev,      // [201,N,N]
    const float* __restrict__ ub,      // [N,N,3]
    const float* __restrict__ a,       // [T,N,N,3]
    const float* __restrict__ w,       // [T,N,1,N]
    const float* __restrict__ lw,      // [N,3]
    const float* __restrict__ lb,      // [N]
    float* __restrict__ out)           // [S,N,N]
{
    __shared__ float2 fs2[SS];         // fs2[s] = {f[2s], f[2s+1]}
    float* fsbuf = (float*)fs2;

    const int n    = blockIdx.x;
    const int m    = threadIdx.x;
    const int lane = m & 63;
    const int wid  = m >> 6;

    const size_t TSTRIDE = (size_t)NN * NN * 3;                   // floats per t-slab
    const size_t base    = (size_t)n * (NN * 3) + (size_t)m * 3;  // this chain's offset

    // ---- issue the ring preload FIRST so its HBM latency hides under the
    //      prologue's compute (loads fire early, waits land at first use) ----
    float rg[DD][6];                   // fully static-indexed -> registers
    const float* pf = a + base;
    {
#pragma unroll
        for (int j = 0; j < DD; ++j) {
            rg[j][0] = pf[0];
            rg[j][1] = pf[1];
            rg[j][2] = pf[2];
            rg[j][3] = pf[TSTRIDE + 0];
            rg[j][4] = pf[TSTRIDE + 1];
            rg[j][5] = pf[TSTRIDE + 2];
            pf += 2 * TSTRIDE;         // pf ends at step DD
        }
    }
    // keep the preload loads ABOVE the prologue in the emitted code
    asm volatile("" ::: "memory");

    const float t0 = timep[0];
    const float t1 = timep[1];
    // wave `wid` handles t = wid + 4k -> parity of t is wid&1 (wave-uniform)
    const float tsel = (wid & 1) ? t1 : t0;

    // ---- prologue: f[t] = exp(-dot(w[t,n,0,:], ev[t,n,:]) * time[t&1]) ----
    // 4 waves, each owns 50 t's; 5 t's per iteration (t, t+4, ..., t+16) for
    // deep memory-level parallelism; unroll 2 doubles in-flight loads.
    {
        const size_t rowoff = (size_t)n * NN;
        const float* wrow = w  + rowoff;
        const float* erow = ev + rowoff;
#pragma unroll 2
        for (int t = wid; t < TT; t += 20) {
            float d[5];
#pragma unroll
            for (int q = 0; q < 5; ++q) {
                const int tq = t + 4 * q;                  // max = wid+196 <= 199
                float4 wv = ((const float4*)(wrow + (size_t)tq * (NN * NN)))[lane];
                float4 evv = ((const float4*)(erow + (size_t)tq * (NN * NN)))[lane];
                float dq = wv.x * evv.x;
                dq = fmaf(wv.y, evv.y, dq);
                dq = fmaf(wv.z, evv.z, dq);
                dq = fmaf(wv.w, evv.w, dq);
                d[q] = dq;
            }
#pragma unroll
            for (int off = 1; off < 64; off <<= 1) {
#pragma unroll
                for (int q = 0; q < 5; ++q)
                    d[q] += __shfl_xor(d[q], off, 64);
            }
            if (lane == 0) {
#pragma unroll
                for (int q = 0; q < 5; ++q)
                    fsbuf[t + 4 * q] = __expf(-d[q] * tsel);
            }
        }
    }

    // per-node epilogue constants (n is block-uniform -> scalar loads)
    const float w0 = lw[n * 3 + 0];
    const float w1 = lw[n * 3 + 1];
    const float w2 = lw[n * 3 + 2];
    const float bb = lb[n];

    float u0 = ub[base + 0];
    float u1 = ub[base + 1];
    float u2 = ub[base + 2];

    __syncthreads();

    float* op = out + (size_t)n * NN + m;

    // ---- main scan: depth-DD software pipeline, all ring indices static ----
    for (int g = 0; g < NG - 1; ++g) {
        const int sb = g * DD;
#pragma unroll
        for (int j = 0; j < DD; ++j) {
            const int s = sb + j;
            const float2 ff = fs2[s];
            // consume ring slot j (loaded DD steps ago)
            float l0 = fmaf(rg[j][0], ff.x, fmaf(rg[j][3], ff.y, u0));
            float l1 = fmaf(rg[j][1], ff.x, fmaf(rg[j][4], ff.y, u1));
            float l2 = fmaf(rg[j][2], ff.x, fmaf(rg[j][5], ff.y, u2));
            // rg[j] now dead -> issue prefetch for step s+DD into the same slot
            rg[j][0] = pf[0];
            rg[j][1] = pf[1];
            rg[j][2] = pf[2];
            rg[j][3] = pf[TSTRIDE + 0];
            rg[j][4] = pf[TSTRIDE + 1];
            rg[j][5] = pf[TSTRIDE + 2];
            pf += 2 * TSTRIDE;
            // softmax over the 3 components
            float mx  = fmaxf(l0, fmaxf(l1, l2));
            float e0  = __expf(l0 - mx);
            float e1  = __expf(l1 - mx);
            float e2  = __expf(l2 - mx);
            float inv = __builtin_amdgcn_rcpf(e0 + e1 + e2);
            u0 = e0 * inv;
            u1 = e1 * inv;
            u2 = e2 * inv;
            __builtin_nontemporal_store(
                fmaf(u0, w0, fmaf(u1, w1, fmaf(u2, w2, bb))),
                op + (size_t)s * (NN * NN));
        }
    }
    // last group: consume only (no prefetch, no tail over-read)
    {
        const int sb = (NG - 1) * DD;
#pragma unroll
        for (int j = 0; j < DD; ++j) {
            const int s = sb + j;
            const float2 ff = fs2[s];
            float l0 = fmaf(rg[j][0], ff.x, fmaf(rg[j][3], ff.y, u0));
            float l1 = fmaf(rg[j][1], ff.x, fmaf(rg[j][4], ff.y, u1));
            float l2 = fmaf(rg[j][2], ff.x, fmaf(rg[j][5], ff.y, u2));
            float mx  = fmaxf(l0, fmaxf(l1, l2));
            float e0  = __expf(l0 - mx);
            float e1  = __expf(l1 - mx);
            float e2  = __expf(l2 - mx);
            float inv = __builtin_amdgcn_rcpf(e0 + e1 + e2);
            u0 = e0 * inv;
            u1 = e1 * inv;
            u2 = e2 * inv;
            __builtin_nontemporal_store(
                fmaf(u0, w0, fmaf(u1, w1, fmaf(u2, w2, bb))),
                op + (size_t)s * (NN * NN));
        }
    }
}

extern "C" void kernel_launch(void* const* d_in, const int* in_sizes, int n_in,
                              void* d_out, int out_size, void* d_ws, size_t ws_size,
                              hipStream_t stream) {
    const float* timep = (const float*)d_in[0];
    const float* ev    = (const float*)d_in[1];
    const float* ub    = (const float*)d_in[2];
    const float* a     = (const float*)d_in[3];
    const float* w     = (const float*)d_in[4];
    const float* lw    = (const float*)d_in[5];
    const float* lb    = (const float*)d_in[6];
    float* out = (float*)d_out;

    fused_scan_kernel<<<NN, 256, 0, stream>>>(timep, ev, ub, a, w, lw, lb, out);
}